// Round 8
// baseline (2717.602 us; speedup 1.0000x reference)
//
#include <hip/hip_runtime.h>
#include <hip/hip_fp16.h>

typedef _Float16 f16;
typedef _Float16 f16x2 __attribute__((ext_vector_type(2)));
typedef _Float16 f16x8 __attribute__((ext_vector_type(8)));
typedef float    f32x4 __attribute__((ext_vector_type(4)));
typedef unsigned int u32;
typedef unsigned long long u64;

#define BN_EPS 1e-5f

static constexpr int BB  = 32;    // batch
static constexpr int CC  = 128;   // channels
static constexpr int HWN = 1024;  // H*W = L
static constexpr int RIN = 256;
static constexpr int RH  = 512;
static constexpr int OCN = 128;

// ---------------------------------------------------------------- BN stats
__global__ void bn_stats_kernel(const float* __restrict__ x,
                                const float* __restrict__ gamma,
                                const float* __restrict__ beta,
                                float* __restrict__ scale,
                                float* __restrict__ shift) {
    int c = blockIdx.x;
    int tid = threadIdx.x;
    float s = 0.f, s2 = 0.f;
    const float* xc = x + (size_t)c * HWN;
    for (int idx = tid; idx < BB * HWN; idx += 256) {
        int b = idx >> 10, hw = idx & 1023;
        float v = xc[(size_t)b * (CC * HWN) + hw];
        s += v; s2 += v * v;
    }
    for (int off = 32; off > 0; off >>= 1) {
        s  += __shfl_down(s, off, 64);
        s2 += __shfl_down(s2, off, 64);
    }
    __shared__ float ls[4], ls2[4];
    int wv = tid >> 6, ln = tid & 63;
    if (ln == 0) { ls[wv] = s; ls2[wv] = s2; }
    __syncthreads();
    if (tid == 0) {
        float ts  = ls[0] + ls[1] + ls[2] + ls[3];
        float ts2 = ls2[0] + ls2[1] + ls2[2] + ls2[3];
        const float inv_n = 1.0f / (BB * HWN);
        float mean = ts * inv_n;
        float var  = ts2 * inv_n - mean * mean;
        float rstd = rsqrtf(var + BN_EPS);
        float sc = gamma[c] * rstd;
        scale[c] = sc;
        shift[c] = beta[c] - mean * sc;
    }
}

// ------------------------------------------- normalize + transpose -> A1 f16
__global__ void prep_x_kernel(const float* __restrict__ x,
                              const float* __restrict__ scale,
                              const float* __restrict__ shift,
                              f16* __restrict__ A1) {
    __shared__ float tile[32][33];
    int tx = threadIdx.x, ty = threadIdx.y;  // 32 x 8
    int hb = blockIdx.x, cb = blockIdx.y, b = blockIdx.z;
    #pragma unroll
    for (int k = 0; k < 4; k++) {
        int c  = cb * 32 + ty + 8 * k;
        int hw = hb * 32 + tx;
        tile[ty + 8 * k][tx] = x[(size_t)b * (CC * HWN) + (size_t)c * HWN + hw];
    }
    __syncthreads();
    #pragma unroll
    for (int k = 0; k < 4; k++) {
        int hw = hb * 32 + ty + 8 * k;
        int c  = cb * 32 + tx;
        float v = tile[tx][ty + 8 * k];
        A1[(size_t)(b * HWN + hw) * CC + c] = (f16)(v * scale[c] + shift[c]);
    }
}

// ------------------------------------------------------------ weight prep
// wr layout (R6/R7-verified): u32 idx = (slot*512+t)*4+e, slot = 8j+i.
// Thread t: rows 8*(t>>3)+j, chunk c=t&7 (h-pairs [32c,32c+32)).
// Element e of dwordx4 i covers h-pair p = 32c + 4*(i XOR c) + e.
__global__ void prep_w_kernel(const float* __restrict__ w_in,
                              const float* __restrict__ w_ih,
                              const float* __restrict__ w_out,
                              const float* __restrict__ w_hh,
                              const float* __restrict__ b_ih,
                              const float* __restrict__ b_hh,
                              f16* __restrict__ w_in_h,
                              f16* __restrict__ w_ih_h,
                              f16* __restrict__ w_out_h,
                              u32* __restrict__ wr,
                              float* __restrict__ bihh) {
    int idx = blockIdx.x * 256 + threadIdx.x;
    if (idx < 32768) { w_in_h[idx] = (f16)w_in[idx]; return; }
    idx -= 32768;
    if (idx < 131072) { w_ih_h[idx] = (f16)w_ih[idx]; return; }
    idx -= 131072;
    if (idx < 65536) { w_out_h[idx] = (f16)w_out[idx]; return; }
    idx -= 65536;
    if (idx < 131072) {
        int e = idx & 3, q = idx >> 2;
        int t = q & 511, slot = q >> 9;      // slot 0..63
        int i = slot & 7, j = slot >> 3;     // i: dwordx4, j: local row
        int c = t & 7, g = t >> 3;
        int row = (g << 3) + j;              // output row 0..511
        int p = (c << 5) + ((i ^ c) << 2) + e;  // h-pair index
        f16 lo = (f16)w_hh[(size_t)row * 512 + 2 * p];
        f16 hi = (f16)w_hh[(size_t)row * 512 + 2 * p + 1];
        wr[idx] = (u32)__builtin_bit_cast(unsigned short, lo) |
                  ((u32)__builtin_bit_cast(unsigned short, hi) << 16);
        return;
    }
    idx -= 131072;
    if (idx < 512) { bihh[idx] = b_ih[idx] + b_hh[idx]; return; }
}

// ------------------------------------------------------------- MFMA GEMM
template <int MODE>
__global__ void gemm_kernel(const f16* __restrict__ A,
                            const f16* __restrict__ W,
                            const float* __restrict__ bias,
                            void* __restrict__ outp,
                            int N, int K) {
    int wave = threadIdx.x >> 6;
    int lane = threadIdx.x & 63;
    int q = lane >> 4, r = lane & 15;
    int bm = blockIdx.x * 256 + wave * 64;
    int bn = blockIdx.y * 64;

    f32x4 acc[4][4];
    #pragma unroll
    for (int i = 0; i < 4; i++)
        #pragma unroll
        for (int j = 0; j < 4; j++)
            acc[i][j] = (f32x4){0.f, 0.f, 0.f, 0.f};

    const f16* Ap = A + (size_t)(bm + r) * K + 8 * q;
    const f16* Wp = W + (size_t)(bn + r) * K + 8 * q;

    for (int k = 0; k < K; k += 32) {
        f16x8 av[4], bv[4];
        #pragma unroll
        for (int i = 0; i < 4; i++)
            av[i] = *(const f16x8*)(Ap + (size_t)(16 * i) * K + k);
        #pragma unroll
        for (int i = 0; i < 4; i++)
            bv[i] = *(const f16x8*)(Wp + (size_t)(16 * i) * K + k);
        #pragma unroll
        for (int mi = 0; mi < 4; mi++)
            #pragma unroll
            for (int ni = 0; ni < 4; ni++)
                acc[mi][ni] = __builtin_amdgcn_mfma_f32_16x16x32_f16(
                    av[mi], bv[ni], acc[mi][ni], 0, 0, 0);
    }

    #pragma unroll
    for (int mi = 0; mi < 4; mi++) {
        #pragma unroll
        for (int ni = 0; ni < 4; ni++) {
            int col = bn + 16 * ni + r;
            float bval = bias[col];
            #pragma unroll
            for (int i = 0; i < 4; i++) {
                int row = bm + 16 * mi + 4 * q + i;
                float val = acc[mi][ni][i] + bval;
                if (MODE == 0) {
                    val = val - tanhf(val);
                    ((f16*)outp)[(size_t)row * N + col] = (f16)val;
                } else if (MODE == 1) {
                    ((f16*)outp)[(size_t)row * N + col] = (f16)val;
                } else {
                    int b = row >> 10, hw = row & 1023;
                    ((float*)outp)[(size_t)b * (OCN * HWN) + (size_t)col * HWN + hw] = val;
                }
            }
        }
    }
}

// ---------------------------------------------------------------- RNN scan
// R8: batch-per-CU (zero cross-WG comm) with resident weights in AGPRs.
// R7 post-mortem: "+v" pin + waves_per_eu(2,2) STILL spilled (VGPR 116 <
// the 160 resident words) -- the pin blocks remat, not spill, and the
// backend's occupancy heuristic keeps targeting ~4 waves/EU. THIS round:
// rows j=0..4 (160 u32/thread) live in AGPRs via hard "a" inline-asm
// constraints (v_accvgpr_write at init, volatile v_accvgpr_read in-loop).
// The occupancy heuristic cannot shrink 160 asm-constrained AGPRs below
// 256-total -> residency is structurally forced. VGPR side stays ~75.
// Cost: 160 accvgpr_read/thread/step (+640 cyc/SIMD) on top of 256 dot2
// (1024 cyc) -> step ~2000 cyc vs R7's ~5000 spill mode.
//  * rows j=5,6 (128KB): LDS, quad-swizzled slot (q+t)&15.
//  * row  j=7  (64KB/step): streamed from L2, two 4-quad halves.
//  * k-loop over 8 h-quads, XOR-swizzled conflict-free h broadcast.
//  * butterfly reduce-scatter -> lane t owns row t; 1 barrier/step.
__device__ __forceinline__ float dot2acc(u32 w, f16x2 h, float c) {
#if __has_builtin(__builtin_amdgcn_fdot2)
    return __builtin_amdgcn_fdot2(__builtin_bit_cast(f16x2, w), h, c, false);
#else
    f16x2 a = __builtin_bit_cast(f16x2, w);
    return c + (float)a[0] * (float)h[0] + (float)a[1] * (float)h[1];
#endif
}

__device__ __forceinline__ f16x2 u2h(u32 w) { return __builtin_bit_cast(f16x2, w); }

// load one weight quad (row j, k-slot k) and park it in 4 AGPRs
#define LWA(j,k)                                                             \
    u32 A##j##k##x, A##j##k##y, A##j##k##z, A##j##k##w;                      \
    {   uint4 q = wr4[(((j) * 8 + (k)) << 9) + t];                           \
        asm volatile("v_accvgpr_write_b32 %0, %1" : "=a"(A##j##k##x) : "v"(q.x)); \
        asm volatile("v_accvgpr_write_b32 %0, %1" : "=a"(A##j##k##y) : "v"(q.y)); \
        asm volatile("v_accvgpr_write_b32 %0, %1" : "=a"(A##j##k##z) : "v"(q.z)); \
        asm volatile("v_accvgpr_write_b32 %0, %1" : "=a"(A##j##k##w) : "v"(q.w)); \
    }

// dot a resident (AGPR) quad against h-quad H: 4 volatile reads + 4 dot2
#define DOTA(ACC, j, k, H)                                                   \
    {   u32 w0_, w1_, w2_, w3_;                                              \
        asm volatile("v_accvgpr_read_b32 %0, %1" : "=v"(w0_) : "a"(A##j##k##x)); \
        asm volatile("v_accvgpr_read_b32 %0, %1" : "=v"(w1_) : "a"(A##j##k##y)); \
        asm volatile("v_accvgpr_read_b32 %0, %1" : "=v"(w2_) : "a"(A##j##k##z)); \
        asm volatile("v_accvgpr_read_b32 %0, %1" : "=v"(w3_) : "a"(A##j##k##w)); \
        ACC = dot2acc(w0_, u2h(H.x), ACC);                                   \
        ACC = dot2acc(w1_, u2h(H.y), ACC);                                   \
        ACC = dot2acc(w2_, u2h(H.z), ACC);                                   \
        ACC = dot2acc(w3_, u2h(H.w), ACC);                                   \
    }

#define DOTQ(ACC, V, H)                                                      \
    ACC = dot2acc(V.x, u2h(H.x), ACC);                                       \
    ACC = dot2acc(V.y, u2h(H.y), ACC);                                       \
    ACC = dot2acc(V.z, u2h(H.z), ACC);                                       \
    ACC = dot2acc(V.w, u2h(H.w), ACC);

// one k-step: h-quad k^c, AGPR rows j=0..4, LDS rows j=5,6, stream row j=7
#define KSTEP(k, SV)                                                         \
{   uint4 hq = *(const uint4*)(hb + (c << 7) + (((k) ^ c) << 4));            \
    uint4 w5 = *(const uint4*)(wl + (((((k)      ) + t) & 15) << 4));        \
    uint4 w6 = *(const uint4*)(wl + (((((k) +  8 ) + t) & 15) << 4));        \
    DOTA(a0, 0, k, hq) DOTA(a1, 1, k, hq) DOTA(a2, 2, k, hq)                 \
    DOTA(a3, 3, k, hq) DOTA(a4, 4, k, hq)                                    \
    DOTQ(a5, w5, hq) DOTQ(a6, w6, hq) DOTQ(a7, SV, hq) }

__global__ void __launch_bounds__(512)
__attribute__((amdgpu_waves_per_eu(2, 2)))
rnn_kernel(const u32* WR, f16* __restrict__ xh) {
    const int b = blockIdx.x;     // batch
    const int t = threadIdx.x;    // finalize row t; chunk c = t&7
    const int c = t & 7;

    // [0,512): h double-buffer (2 parities x 256 u32); [512,33280): weights
    __shared__ __align__(16) u32 shm[33280];   // 130 KB

    const uint4* wr4 = (const uint4*)WR;

    // ---- resident rows j=0..4 (slots 0..39): 160 u32 -> AGPRs
    // sched_barrier between rows caps init-time VGPR clustering.
    LWA(0,0) LWA(0,1) LWA(0,2) LWA(0,3) LWA(0,4) LWA(0,5) LWA(0,6) LWA(0,7)
    __builtin_amdgcn_sched_barrier(0);
    LWA(1,0) LWA(1,1) LWA(1,2) LWA(1,3) LWA(1,4) LWA(1,5) LWA(1,6) LWA(1,7)
    __builtin_amdgcn_sched_barrier(0);
    LWA(2,0) LWA(2,1) LWA(2,2) LWA(2,3) LWA(2,4) LWA(2,5) LWA(2,6) LWA(2,7)
    __builtin_amdgcn_sched_barrier(0);
    LWA(3,0) LWA(3,1) LWA(3,2) LWA(3,3) LWA(3,4) LWA(3,5) LWA(3,6) LWA(3,7)
    __builtin_amdgcn_sched_barrier(0);
    LWA(4,0) LWA(4,1) LWA(4,2) LWA(4,3) LWA(4,4) LWA(4,5) LWA(4,6) LWA(4,7)
    __builtin_amdgcn_sched_barrier(0);

    // ---- rows j=5,6 (slots 40..55) -> LDS, quad-swizzled (q+t)&15
    char* wldst = (char*)shm + 2048 + (t << 8);
    #pragma unroll
    for (int q = 0; q < 16; q++) {
        uint4 v = wr4[((40 + q) << 9) + t];
        *(uint4*)(wldst + (((q + t) & 15) << 4)) = v;
    }
    shm[t] = 0u;                  // zero both h parities (512 u32)
    __syncthreads();

    f16* xg = xh + (size_t)b * (HWN * RH);
    const char* wl    = (const char*)shm + 2048 + (t << 8);
    const char* hbase = (const char*)shm;
    const uint4* s7   = wr4 + (56 << 9);    // row j=7 (slots 56..63)
    const bool s0 = (c & 1) != 0, s1 = (c & 2) != 0, s2 = (c & 4) != 0;

    for (int step = 0; step < HWN; step++) {
        // LICM guard: stream base poisoned -> loads stay inside the loop
        unsigned long long s7a = (unsigned long long)s7;
        asm volatile("" : "+v"(s7a));
        const uint4* s7v = (const uint4*)s7a;
        uint4 v0 = s7v[t],          v1 = s7v[512 + t],
              v2 = s7v[1024 + t],   v3 = s7v[1536 + t];

        float xcur = (float)xg[(size_t)step * RH + t];

        const char* hb = hbase + ((step & 1) << 10);
        float a0 = 0.f, a1 = 0.f, a2 = 0.f, a3 = 0.f;
        float a4 = 0.f, a5 = 0.f, a6 = 0.f, a7 = 0.f;

        KSTEP(0, v0) KSTEP(1, v1)
        uint4 v4 = s7v[2048 + t], v5 = s7v[2560 + t],
              v6 = s7v[3072 + t], v7 = s7v[3584 + t];
        KSTEP(2, v2) KSTEP(3, v3)
        KSTEP(4, v4) KSTEP(5, v5) KSTEP(6, v6) KSTEP(7, v7)

        // ---- butterfly reduce-scatter (R6-verified): lane c gets row j==c
        float x01 = __shfl_xor(s0 ? a0 : a1, 1, 64);
        float n01 = (s0 ? a1 : a0) + x01;
        float x23 = __shfl_xor(s0 ? a2 : a3, 1, 64);
        float n23 = (s0 ? a3 : a2) + x23;
        float x45 = __shfl_xor(s0 ? a4 : a5, 1, 64);
        float n45 = (s0 ? a5 : a4) + x45;
        float x67 = __shfl_xor(s0 ? a6 : a7, 1, 64);
        float n67 = (s0 ? a7 : a6) + x67;

        float xA = __shfl_xor(s1 ? n01 : n23, 2, 64);
        float mA = (s1 ? n23 : n01) + xA;
        float xB = __shfl_xor(s1 ? n45 : n67, 2, 64);
        float mB = (s1 ? n67 : n45) + xB;

        float xC = __shfl_xor(s2 ? mA : mB, 4, 64);
        float my = (s2 ? mB : mA) + xC;

        float h = tanhf(xcur + my);
        f16 hf = (f16)h;
        ((f16*)(hbase + (((step & 1) ^ 1) << 10)))[t] = hf;   // next-step h
        xg[(size_t)step * RH + t] = hf;                        // hs output
        __syncthreads();
    }
}

// ------------------------------------------------------------------ launch
extern "C" void kernel_launch(void* const* d_in, const int* in_sizes, int n_in,
                              void* d_out, int out_size, void* d_ws, size_t ws_size,
                              hipStream_t stream) {
    const float* x     = (const float*)d_in[0];
    const float* gamma = (const float*)d_in[1];
    const float* beta  = (const float*)d_in[2];
    const float* w_in  = (const float*)d_in[3];
    const float* b_in  = (const float*)d_in[4];
    const float* w_ih  = (const float*)d_in[5];
    const float* b_ih  = (const float*)d_in[6];
    const float* w_hh  = (const float*)d_in[7];
    const float* b_hh  = (const float*)d_in[8];
    const float* w_out = (const float*)d_in[9];
    const float* b_out = (const float*)d_in[10];

    char* ws = (char*)d_ws;
    float* scale   = (float*)(ws + 0);         //   512 B
    float* shift   = (float*)(ws + 512);       //   512 B
    float* bihh    = (float*)(ws + 1024);      //  2 KB
    f16*   w_in_h  = (f16*)(ws + 4096);        // 64 KB
    f16*   w_ih_h  = (f16*)(ws + 69632);       // 256 KB
    f16*   w_out_h = (f16*)(ws + 331776);      // 128 KB
    u32*   wr      = (u32*)(ws + 462848);      // 512 KB packed W_hh
    f16*   xh      = (f16*)(ws + 1179648);     // 32 MB xgate, overwritten by hs
    f16*   A1      = (f16*)(ws + 34734080);    //  8 MB
    f16*   inp     = (f16*)(ws + 43122688);    // 16 MB (ends 59899904)

    bn_stats_kernel<<<128, 256, 0, stream>>>(x, gamma, beta, scale, shift);
    prep_w_kernel<<<1410, 256, 0, stream>>>(w_in, w_ih, w_out, w_hh, b_ih, b_hh,
                                            w_in_h, w_ih_h, w_out_h, wr, bihh);
    prep_x_kernel<<<dim3(32, 4, 32), dim3(32, 8), 0, stream>>>(x, scale, shift, A1);
    gemm_kernel<0><<<dim3(128, 4), 256, 0, stream>>>(A1, w_in_h, b_in, (void*)inp, RIN, CC);
    gemm_kernel<1><<<dim3(128, 8), 256, 0, stream>>>(inp, w_ih_h, bihh, (void*)xh, RH, RIN);
    rnn_kernel<<<32, 512, 0, stream>>>(wr, xh);
    gemm_kernel<2><<<dim3(128, 2), 256, 0, stream>>>(xh, w_out_h, b_out, d_out, OCN, RH);
}